// Round 15
// baseline (335.811 us; speedup 1.0000x reference)
//
#include <hip/hip_runtime.h>
#include <math.h>

#define ND 16
#define NSZ 384
#define NHALF 192
#define NPIX 147456    // 384*384
#define QPIX 36864     // 192*192
#define MS2 1024
#define NG 194
#define EPSV 0.001f

// load element i of a buffer that is f64 (flag=1) or f32 (flag=0)
__device__ __forceinline__ double ld64(const void* p, long i, int f){
  return f ? ((const double*)p)[i] : (double)((const float*)p)[i];
}
// dtype detect inline
__device__ __forceinline__ int dtflag(const void* rg){
  double d = ((const double*)rg)[1];
  return (fabs(d) < 1.0e9) ? 1 : 0;
}

// ---------------- twiddles (SoA): twr[j]=cos, twi[j]=-sin (e^{-2pi i j/384})
__device__ __forceinline__ void init_tws(float* twr, float* twi){
  for (int j=(int)threadIdx.x; j<NSZ; j+=(int)blockDim.x){
    double s,c; sincos((2.0*M_PI/384.0)*(double)j, &s, &c);
    twr[j]=(float)c; twi[j]=(float)(-s);
  }
}

// ------- SINGLE-BUFFER SoA Stockham FFT, N=384=3*2^7, 64 thr/transform ------
// Per stage: read inputs to regs -> barrier -> write outputs -> barrier.
// Result in the same (br,bi) buffer. Caller must barrier after staging.
template<int STR,int DIR>
__device__ __forceinline__ void fftsb(float* br,float* bi,int u,
                                      const float* twr,const float* twi){
  const float KH = (DIR>0)?0.86602540378443865f:-0.86602540378443865f;
  // ---- radix-3 stage ----
  {
    float ar[2],ai[2],brv[2],biv[2],crv[2],civ[2];
    #pragma unroll
    for (int t=0;t<2;t++){
      int p=u+64*t;
      ar[t]=br[p*STR];        ai[t]=bi[p*STR];
      brv[t]=br[(p+128)*STR]; biv[t]=bi[(p+128)*STR];
      crv[t]=br[(p+256)*STR]; civ[t]=bi[(p+256)*STR];
    }
    __syncthreads();
    #pragma unroll
    for (int t=0;t<2;t++){
      int p=u+64*t;
      float t1r=brv[t]+crv[t],t1i=biv[t]+civ[t];
      float y0r=ar[t]+t1r,y0i=ai[t]+t1i;
      float t2r=ar[t]-0.5f*t1r,t2i=ai[t]-0.5f*t1i;
      float bdr=brv[t]-crv[t],bdi=biv[t]-civ[t];
      float t3r=KH*bdi,t3i=-KH*bdr;
      float w1r=twr[p],   w1i=(DIR>0)?twi[p]:-twi[p];
      float w2r=twr[2*p], w2i=(DIR>0)?twi[2*p]:-twi[2*p];
      float y1r=t2r+t3r,y1i=t2i+t3i;
      float y2r=t2r-t3r,y2i=t2i-t3i;
      br[(3*p  )*STR]=y0r;             bi[(3*p  )*STR]=y0i;
      br[(3*p+1)*STR]=y1r*w1r-y1i*w1i; bi[(3*p+1)*STR]=y1r*w1i+y1i*w1r;
      br[(3*p+2)*STR]=y2r*w2r-y2i*w2i; bi[(3*p+2)*STR]=y2r*w2i+y2i*w2r;
    }
    __syncthreads();
  }
  // ---- 7 radix-2 stages ----
  #pragma unroll
  for (int st=0; st<7; st++){
    const int s = 3<<st;
    float ar[3],ai[3],br2[3],bi2[3];
    #pragma unroll
    for (int t=0;t<3;t++){
      int i=u+64*t;
      ar[t]=br[i*STR];        ai[t]=bi[i*STR];
      br2[t]=br[(i+192)*STR]; bi2[t]=bi[(i+192)*STR];
    }
    __syncthreads();
    #pragma unroll
    for (int t=0;t<3;t++){
      int i=u+64*t, p=i/s, tt=p*s;
      float wr=twr[tt], wi=(DIR>0)?twi[tt]:-twi[tt];
      float sur=ar[t]+br2[t],sui=ai[t]+bi2[t];
      float dr=ar[t]-br2[t],di=ai[t]-bi2[t];
      int o=i+tt;
      br[o*STR]=sur;             bi[o*STR]=sui;
      br[(o+s)*STR]=dr*wr-di*wi; bi[(o+s)*STR]=dr*wi+di*wr;
    }
    __syncthreads();
  }
}

// ---------------- K1: fused trig + dot partials -----------------------------
__global__ __launch_bounds__(256) void k_dotA(const void* __restrict__ h1d,
    const void* __restrict__ amp, const void* __restrict__ pph,
    const void* __restrict__ Hm, const void* __restrict__ rg,
    double2* __restrict__ part){
  int wd = blockIdx.x >> 3, ch = blockIdx.x & 7;
  int w = wd >> 4;
  int f = dtflag(rg);
  int m0 = ch << 7;
  __shared__ double sac[128], sas[128];
  int tid = (int)threadIdx.x;
  if (tid < 128){
    double wl = (w==0) ? 6.32e-07 : (w==1 ? 5.5e-07 : 4.5e-07);
    double um2 = (wl*1e6)*(wl*1e6);
    double n_idx = 1.5375 + 0.00829045/um2 - 0.000211046/(um2*um2);
    double coef = (2.0*M_PI/wl)*(n_idx-1.0);
    long mi = m0 + tid;
    double h = ld64(h1d, mi, f);
    double a = ld64(amp, (long)wd*MS2 + mi, f);
    double p = ld64(pph, (long)wd*MS2 + mi, f);
    double s,c; sincos(coef*h + p, &s, &c);
    sac[tid] = a*c; sas[tid] = a*s;
  }
  __syncthreads();
  int r = tid;
  if (r < NG){
    double sr=0.0, si=0.0;
    if (f){
      const double* Hw = (const double*)Hm + ((size_t)w*MS2 + m0)*NG + r;
      #pragma unroll 4
      for (int m=0;m<128;m++){
        double h = Hw[(size_t)m*NG];
        sr += sac[m]*h; si += sas[m]*h;
      }
    } else {
      const float* Hw = (const float*)Hm + ((size_t)w*MS2 + m0)*NG + r;
      #pragma unroll 4
      for (int m=0;m<128;m++){
        double h = (double)Hw[(size_t)m*NG];
        sr += sac[m]*h; si += sas[m]*h;
      }
    }
    part[(size_t)blockIdx.x*NG + r] = make_double2(sr, si);
  }
}

// ---------------- K2: fused dot-reduce + interp + quadrant sum --------------
__global__ __launch_bounds__(256) void k_interp2(const double2* __restrict__ part,
    const void* __restrict__ rg, const void* __restrict__ rs,
    float* __restrict__ q, double* __restrict__ sums_b){
  int wdl = blockIdx.x / 144, blk = blockIdx.x % 144;
  int c = wdl >> 4;
  int pix = blk*256 + (int)threadIdx.x;     // 0..36863
  int f = dtflag(rg);
  __shared__ double v[NG];
  int tid = (int)threadIdx.x;
  if (tid < NG){
    double sr=0.0, si=0.0;
    #pragma unroll
    for (int ch=0; ch<8; ch++){
      double2 pp = part[(size_t)(wdl*8+ch)*NG + tid];
      sr += pp.x; si += pp.y;
    }
    v[tid] = sr*sr + si*si;
  }
  __syncthreads();
  long gbase = (long)c*NG;
  double rho = ld64(rs, (long)c*QPIX + pix, f);
  double g0 = ld64(rg, gbase, f);
  double delta = ld64(rg, gbase+1, f) - g0;
  int i = (int)floor((rho-g0)/delta);
  if (i < 0) i = 0; if (i > 192) i = 192;
  double gi  = ld64(rg, gbase+i,   f);
  double gi1 = ld64(rg, gbase+i+1, f);
  if (i > 0  && rho < gi)  { i--; gi1 = gi; gi = ld64(rg, gbase+i, f); }
  else if (i < 192 && rho > gi1){ i++; gi = gi1; gi1 = ld64(rg, gbase+i+1, f); }
  double gl = ld64(rg, gbase+NG-1, f);
  double val;
  if (rho <= g0)      val = v[0];
  else if (rho >= gl) val = v[NG-1];
  else { double t = (rho-gi)/(gi1-gi); val = v[i] + (v[i+1]-v[i])*t; }
  if (val < 0.0) val = 0.0;
  q[(size_t)wdl*QPIX + pix] = (float)val;
  __shared__ double red[256];
  red[threadIdx.x] = val;
  __syncthreads();
  for (int s=128; s>0; s>>=1){
    if ((int)threadIdx.x < s) red[threadIdx.x] += red[threadIdx.x+s];
    __syncthreads();
  }
  if (threadIdx.x==0) atomicAdd(&sums_b[wdl], red[0]);
}

// ---------------- merged forward ROW pass (single-buffer FFT) ---------------
__global__ __launch_bounds__(256) void k_rows_fwd(
    const float* __restrict__ q, const double* __restrict__ sums,
    float* __restrict__ Rr, const float* __restrict__ img,
    const float* __restrict__ depth, float2* __restrict__ V,
    float2* __restrict__ S){
  __shared__ float br[NSZ*5], bis[NSZ*5];
  __shared__ float twr[NSZ], twi[NSZ];
  init_tws(twr, twi);
  int bi = blockIdx.x;
  int rl = (int)threadIdx.x>>6, u = (int)threadIdx.x&63;
  float *xr=br+rl, *xi=bis+rl;
  if (bi < 48*24){
    int imgi = bi/24, t = bi%24;
    int y0 = t*8 + 2*rl;
    float sc = (float)(1.0/(4.0*sums[imgi]*147456.0));
    const float* q0 = q + ((size_t)imgi*QPIX + (size_t)y0*NHALF);
    const float* q1 = q0 + NHALF;
    #pragma unroll
    for (int k=0;k<6;k++){
      int x = u+64*k;
      int gx = (x<NHALF)? x : (383-x);
      xr[x*5] = q0[gx]*sc;
      xi[x*5] = q1[gx]*sc;
    }
    __syncthreads();
    fftsb<5,1>(xr,xi,u,twr,twi);
    const float PC=0.86602540378443865f, PS=-0.5f;   // e^{-i pi/6}
    float s0,c0; __sincosf((float)M_PI*(float)u/384.0f,&s0,&c0);
    float phr=c0, phi=-s0;                            // e^{-i pi kx/384}
    float* o0 = Rr + ((size_t)imgi*192 + y0)*NSZ;
    float* o1 = o0 + NSZ;
    #pragma unroll
    for (int k=0;k<6;k++){
      int kx = u+64*k;
      int m  = kx ? (384-kx) : 0;
      float Zr=xr[kx*5], Zi=xi[kx*5], Zmr=xr[m*5], Zmi=xi[m*5];
      float Ar=0.5f*(Zr+Zmr), Ai=0.5f*(Zi-Zmi);
      float Br=0.5f*(Zi+Zmi), Bi=-0.5f*(Zr-Zmr);
      o0[kx] = Ar*phr - Ai*phi;
      o1[kx] = Br*phr - Bi*phi;
      float nr=phr*PC-phi*PS, ni=phr*PS+phi*PC; phr=nr; phi=ni;
    }
  } else if (bi < 48*24 + 48*96){
    int i2 = bi - 48*24;
    int im48 = i2/96, grp = i2%96;
    int c = im48>>4, d = im48&15;
    int y = grp*4 + rl;
    const float* i0 = img + (((size_t)0*3+c)*NPIX + (size_t)y*NSZ);
    const float* i1 = img + (((size_t)1*3+c)*NPIX + (size_t)y*NSZ);
    const float* d0 = depth + (size_t)y*NSZ;
    const float* d1 = depth + (size_t)NPIX + (size_t)y*NSZ;
    #pragma unroll
    for (int k=0;k<6;k++){
      int x=u+64*k;
      int ia=(int)floorf(d0[x]*16.f); ia=ia<0?0:(ia>15?15:ia);
      int ib=(int)floorf(d1[x]*16.f); ib=ib<0?0:(ib>15?15:ib);
      xr[x*5] = (ia==d)? i0[x] : 0.f;
      xi[x*5] = (ib==d)? i1[x] : 0.f;
    }
    __syncthreads();
    fftsb<5,1>(xr,xi,u,twr,twi);
    float2* orow = V + ((size_t)im48*NPIX + (size_t)y*NSZ);
    #pragma unroll
    for (int k=0;k<6;k++){ int x=u+64*k; orow[x]=make_float2(xr[x*5],xi[x*5]); }
  } else {
    int i3 = bi - 48*24 - 48*96;
    int d = i3/96, grp = i3%96;            // d in [0,16): batch-packed layered
    int y = grp*4+rl;
    const float* d0 = depth + (size_t)y*NSZ;
    const float* d1 = depth + (size_t)NPIX + (size_t)y*NSZ;
    #pragma unroll
    for (int k=0;k<6;k++){
      int x=u+64*k;
      int ia=(int)floorf(d0[x]*16.f); ia=ia<0?0:(ia>15?15:ia);
      int ib=(int)floorf(d1[x]*16.f); ib=ib<0?0:(ib>15?15:ib);
      xr[x*5]=(ia==d)?1.f:0.f;
      xi[x*5]=(ib==d)?1.f:0.f;
    }
    __syncthreads();
    fftsb<5,1>(xr,xi,u,twr,twi);
    float2* orow = S + ((size_t)d*NPIX + (size_t)y*NSZ);
    #pragma unroll
    for (int k=0;k<6;k++){ int x=u+64*k; orow[x]=make_float2(xr[x*5],xi[x*5]); }
  }
}

// ---------------- merged col pass: F-build (real) + S forward (16 imgs) -----
__global__ __launch_bounds__(512) void k_colsFS(const float* __restrict__ Rr,
    float* __restrict__ Rc, float2* __restrict__ S){
  __shared__ float br[NSZ*9], bis[NSZ*9];
  __shared__ float twr[NSZ], twi[NSZ];
  init_tws(twr,twi);
  int bi = blockIdx.x;
  if (bi < 1152){
    int imgi = bi/24, cg = bi%24;
    int j16 = (int)threadIdx.x&15, r0 = (int)threadIdx.x>>4;   // r0 in [0,32)
    int uu = j16>>1;
    const float* rbase = Rr + (size_t)imgi*192*NSZ + cg*16 + j16;
    #pragma unroll
    for (int k=0;k<12;k++){
      int y = r0 + 32*k;
      int gy = (y<NHALF)? y : (383-y);
      float v = rbase[(size_t)gy*NSZ];
      if (j16&1) bis[y*9+uu]=v; else br[y*9+uu]=v;
    }
    __syncthreads();
    int cc = (int)threadIdx.x>>6, u = (int)threadIdx.x&63;
    fftsb<9,1>(br+cc,bis+cc,u,twr,twi);
    const float PC=0.96592582628906829f, PS=-0.25881904510252076f; // e^{-i pi/12}
    float s0,c0; __sincosf((float)M_PI*(float)r0/384.f,&s0,&c0);
    float phr=c0, phi=-s0;
    float* ob = Rc + (size_t)imgi*NPIX + cg*16 + j16;
    #pragma unroll
    for (int k=0;k<12;k++){
      int ky=r0+32*k;
      int m = ky ? (384-ky) : 0;
      float Zr=br[ky*9+uu], Zi=bis[ky*9+uu], Zmr=br[m*9+uu], Zmi=bis[m*9+uu];
      float Cr,Ci;
      if (j16&1){ Cr=0.5f*(Zi+Zmi); Ci=-0.5f*(Zr-Zmr); }
      else      { Cr=0.5f*(Zr+Zmr); Ci= 0.5f*(Zi-Zmi); }
      ob[(size_t)ky*NSZ] = Cr*phr - Ci*phi;
      float nr=phr*PC-phi*PS, ni=phr*PS+phi*PC; phr=nr; phi=ni;
    }
  } else {
    int i2 = bi - 1152;
    int imgi = i2/48, cg = i2%48;          // imgi in [0,16)
    size_t boff = (size_t)imgi*NPIX + (size_t)cg*8;
    int j = (int)threadIdx.x&7, r0 = (int)threadIdx.x>>3;
    #pragma unroll
    for (int k=0;k<6;k++){
      int r=r0+64*k;
      float2 v = S[boff + (size_t)r*NSZ + j];
      br[r*9+j]=v.x; bis[r*9+j]=v.y;
    }
    __syncthreads();
    int cc=(int)threadIdx.x>>6, u=(int)threadIdx.x&63;
    fftsb<9,1>(br+cc,bis+cc,u,twr,twi);
    #pragma unroll
    for (int k=0;k<6;k++){
      int r=r0+64*k;
      S[boff+(size_t)r*NSZ+j] = make_float2(br[r*9+j], bis[r*9+j]);
    }
  }
}

// ---------------- merged: fused V-convolution + mulinv, 16-col tiles --------
// 1024 thr = 16 FFT units; LDS stride 17 (odd -> 2-way conflicts only).
// bi < nf (=48*24): fwd cols + mul + inv cols on V (16 cols), in place.
// else: mulinv over (c,d,cg16): L[c*ND+d] = icolFFT(S[d]*F[c,d]).
__global__ __launch_bounds__(1024, 8) void k_FM(float2* __restrict__ V,
    const float* __restrict__ Rc, const float2* __restrict__ S,
    float2* __restrict__ L, int nf){
  __shared__ float br[NSZ*17], bis[NSZ*17];
  __shared__ float twr[NSZ], twi[NSZ];
  init_tws(twr,twi);
  const float PC=0.86602540378443865f, PS=0.5f;   // e^{+i pi/6}
  int bi = blockIdx.x;
  int tid = (int)threadIdx.x;
  int j = tid&15, r0 = tid>>4;            // r0 in [0,64)
  int unit = tid>>6, u = tid&63;          // 16 FFT units
  if (bi < nf){
    int imgi = bi/24, cg = bi%24;
    size_t boff = (size_t)imgi*NPIX + (size_t)cg*16;
    #pragma unroll
    for (int k=0;k<6;k++){
      int r=r0+64*k;
      float2 v = V[boff + (size_t)r*NSZ + j];
      br[r*17+j]=v.x; bis[r*17+j]=v.y;
    }
    __syncthreads();
    fftsb<17,1>(br+unit,bis+unit,u,twr,twi);
    int kx = cg*16+j;
    float s0,c0; __sincosf((float)M_PI*(float)(kx+r0)/384.f,&s0,&c0);
    float phr=c0, phi=s0;
    const float* rb = Rc + (size_t)imgi*NPIX + kx;
    #pragma unroll
    for (int k=0;k<6;k++){
      int r=r0+64*k;
      float R = rb[(size_t)r*NSZ];
      float fr=R*phr, fi=R*phi;
      float brv=br[r*17+j], biv=bis[r*17+j];
      br[r*17+j]  = brv*fr - biv*fi;
      bis[r*17+j] = brv*fi + biv*fr;
      float nr=phr*PC-phi*PS, ni=phr*PS+phi*PC; phr=nr; phi=ni;
    }
    __syncthreads();
    fftsb<17,-1>(br+unit,bis+unit,u,twr,twi);
    #pragma unroll
    for (int k=0;k<6;k++){
      int r=r0+64*k;
      V[boff+(size_t)r*NSZ+j] = make_float2(br[r*17+j], bis[r*17+j]);
    }
  } else {
    int t = bi - nf;
    int cg = t%24, d=(t/24)&15, c=t/(24*16);   // c in [0,3)
    const float2* src = S  + ((size_t)d*NPIX + (size_t)cg*16);
    const float*  rb  = Rc + ((size_t)(c*ND+d)*NPIX + cg*16);
    float2*       dst = L  + ((size_t)(c*ND+d)*NPIX + (size_t)cg*16);
    int kx = cg*16+j;
    float s0,c0; __sincosf((float)M_PI*(float)(kx+r0)/384.f,&s0,&c0);
    float phr=c0, phi=s0;
    #pragma unroll
    for (int k=0;k<6;k++){
      int r=r0+64*k;
      float2 v = src[(size_t)r*NSZ + j];
      float R = rb[(size_t)r*NSZ + j];
      float fr=R*phr, fi=R*phi;
      br[r*17+j]  = v.x*fr - v.y*fi;
      bis[r*17+j] = v.x*fi + v.y*fr;
      float nr=phr*PC-phi*PS, ni=phr*PS+phi*PC; phr=nr; phi=ni;
    }
    __syncthreads();
    fftsb<17,-1>(br+unit,bis+unit,u,twr,twi);
    #pragma unroll
    for (int k=0;k<6;k++){
      int r=r0+64*k;
      dst[(size_t)r*NSZ+j] = make_float2(br[r*17+j], bis[r*17+j]);
    }
  }
}

// ---------------- inverse row FFT in place: V (48 imgs) + L (48 imgs) -------
// grid 9216; 4 rows/block; single-buffer FFT -> 18.4KB LDS, 8 blocks/CU.
__global__ __launch_bounds__(256) void k_rowsinv(float2* __restrict__ V,
    float2* __restrict__ L){
  __shared__ float br[NSZ*5], bis[NSZ*5];
  __shared__ float twr[NSZ], twi[NSZ];
  init_tws(twr,twi);
  int bi = blockIdx.x;
  float2* base; int ri;
  if (bi < 4608){ base = V; ri = bi; } else { base = L; ri = bi - 4608; }
  int rl=(int)threadIdx.x>>6, u=(int)threadIdx.x&63;
  float *xr=br+rl,*xi=bis+rl;
  float2* row = base + ((size_t)ri*4 + rl)*NSZ;
  #pragma unroll
  for (int k=0;k<6;k++){ int x=u+64*k; float2 v=row[x]; xr[x*5]=v.x; xi[x*5]=v.y; }
  __syncthreads();
  fftsb<5,-1>(xr,xi,u,twr,twi);
  #pragma unroll
  for (int k=0;k<6;k++){ int x=u+64*k; row[x]=make_float2(xr[x*5],xi[x*5]); }
}

// ---------------- streaming occlusion compositing (no FFT) ------------------
// grid 864 x 256; 2 pixels/thread via float4. L,V SPATIAL (c*ND+d):
// re/im = batch0/batch1. DESCENDING d + Horner (round-11 verified math).
__global__ __launch_bounds__(256) void k_combine(const float2* __restrict__ L,
    const float2* __restrict__ V, float* __restrict__ out){
  int t = blockIdx.x*256 + (int)threadIdx.x;   // < 3*NPIX/2
  int c = t / (NPIX/2);
  int pp = t - c*(NPIX/2);                     // pixel-pair index
  size_t base = (size_t)(c*ND)*NPIX + (size_t)pp*2;
  float A0a=0.f,C0a=0.f,A1a=0.f,C1a=0.f;
  float A0b=0.f,C0b=0.f,A1b=0.f,C1b=0.f;
  for (int d=ND-1; d>=0; --d){
    float4 l = *(const float4*)(L + base + (size_t)d*NPIX);
    float4 v = *(const float4*)(V + base + (size_t)d*NPIX);
    A0a += l.x; A1a += l.y; A0b += l.z; A1b += l.w;
    float ic0a=1.f/(A0a+EPSV), ic1a=1.f/(A1a+EPSV);
    float ic0b=1.f/(A0b+EPSV), ic1b=1.f/(A1b+EPSV);
    C0a = v.x*ic0a + (1.f - l.x*ic0a)*C0a;
    C1a = v.y*ic1a + (1.f - l.y*ic1a)*C1a;
    C0b = v.z*ic0b + (1.f - l.z*ic0b)*C0b;
    C1b = v.w*ic1b + (1.f - l.w*ic1b)*C1b;
  }
  size_t o0 = (size_t)(0*3 + c)*NPIX + (size_t)pp*2;
  size_t o1 = (size_t)(1*3 + c)*NPIX + (size_t)pp*2;
  out[o0]   = C0a; out[o0+1] = C0b;
  out[o1]   = C1a; out[o1+1] = C1b;
}

extern "C" void kernel_launch(void* const* d_in, const int* in_sizes, int n_in,
                              void* d_out, int out_size, void* d_ws, size_t ws_size,
                              hipStream_t stream){
  const float* img   = (const float*)d_in[0];   // (2,3,384,384) f32
  const float* depth = (const float*)d_in[1];   // (2,1,384,384) f32
  const void*  h1d   = d_in[2];                 // (1024,)
  const void*  amp   = d_in[3];                 // (3,16,1024)
  const void*  pph   = d_in[4];                 // (3,16,1024)
  const void*  Hm    = d_in[5];                 // (3,1024,194)
  const void*  rg    = d_in[6];                 // (3,194)
  const void*  rs    = d_in[7];                 // (3,192,192)
  float* out = (float*)d_out;
  (void)in_sizes; (void)n_in; (void)out_size;

  char* ws = (char*)d_ws;
  size_t off = 0;
  auto take = [&](size_t b)->char*{ char* p = ws + off; off += (b + 255) & ~(size_t)255; return p; };
  double*  sums = (double*) take((size_t)48*8);
  double2* part = (double2*)take((size_t)48*8*NG*16);     //  1.19 MB
  float*   q    = (float*)  take((size_t)48*QPIX*4);      //  7.08 MB
  float*   Rr   = (float*)  take((size_t)48*192*NSZ*4);   // 14.16 MB
  float*   Rc   = (float*)  take((size_t)48*NPIX*4);      // 28.31 MB
  float2*  V    = (float2*) take((size_t)48*NPIX*8);      // 56.62 MB
  float2*  S    = (float2*) take((size_t)16*NPIX*8);      // 18.87 MB
  float2*  L    = (float2*) take((size_t)48*NPIX*8);      // 56.62 MB
  if (ws_size < off) return;   // ~183 MB; clean absmax failure, not a fault

  hipMemsetAsync(sums, 0, 48*8, stream);
  k_dotA<<<48*8, 256, 0, stream>>>(h1d, amp, pph, Hm, rg, part);
  k_interp2<<<48*144, 256, 0, stream>>>(part, rg, rs, q, sums);
  k_rows_fwd<<<48*24 + 48*96 + 16*96, 256, 0, stream>>>(q, sums, Rr, img, depth, V, S);
  k_colsFS<<<1152 + 16*48, 512, 0, stream>>>(Rr, Rc, S);
  k_FM<<<48*24 + 3*16*24, 1024, 0, stream>>>(V, Rc, S, L, 48*24);
  k_rowsinv<<<9216, 256, 0, stream>>>(V, L);
  k_combine<<<864, 256, 0, stream>>>(L, V, out);
}

// Round 16
// 326.448 us; speedup vs baseline: 1.0287x; 1.0287x over previous
//
#include <hip/hip_runtime.h>
#include <math.h>

#define ND 16
#define NSZ 384
#define NHALF 192
#define NPIX 147456    // 384*384
#define QPIX 36864     // 192*192
#define MS2 1024
#define NG 194
#define EPSV 0.001f

// load element i of a buffer that is f64 (flag=1) or f32 (flag=0)
__device__ __forceinline__ double ld64(const void* p, long i, int f){
  return f ? ((const double*)p)[i] : (double)((const float*)p)[i];
}
// dtype detect inline
__device__ __forceinline__ int dtflag(const void* rg){
  double d = ((const double*)rg)[1];
  return (fabs(d) < 1.0e9) ? 1 : 0;
}

// ---------------- twiddles (SoA): twr[j]=cos, twi[j]=-sin (e^{-2pi i j/384})
__device__ __forceinline__ void init_tws(float* twr, float* twi){
  for (int j=(int)threadIdx.x; j<NSZ; j+=(int)blockDim.x){
    double s,c; sincos((2.0*M_PI/384.0)*(double)j, &s, &c);
    twr[j]=(float)c; twi[j]=(float)(-s);
  }
}

// ------- SINGLE-BUFFER SoA Stockham FFT, N=384=3*2^7, 64 thr/transform ------
// Per stage: read inputs to regs -> barrier -> write outputs -> barrier.
// Result in the same (br,bi) buffer. Caller must barrier after staging.
template<int STR,int DIR>
__device__ __forceinline__ void fftsb(float* br,float* bi,int u,
                                      const float* twr,const float* twi){
  const float KH = (DIR>0)?0.86602540378443865f:-0.86602540378443865f;
  // ---- radix-3 stage ----
  {
    float ar[2],ai[2],brv[2],biv[2],crv[2],civ[2];
    #pragma unroll
    for (int t=0;t<2;t++){
      int p=u+64*t;
      ar[t]=br[p*STR];        ai[t]=bi[p*STR];
      brv[t]=br[(p+128)*STR]; biv[t]=bi[(p+128)*STR];
      crv[t]=br[(p+256)*STR]; civ[t]=bi[(p+256)*STR];
    }
    __syncthreads();
    #pragma unroll
    for (int t=0;t<2;t++){
      int p=u+64*t;
      float t1r=brv[t]+crv[t],t1i=biv[t]+civ[t];
      float y0r=ar[t]+t1r,y0i=ai[t]+t1i;
      float t2r=ar[t]-0.5f*t1r,t2i=ai[t]-0.5f*t1i;
      float bdr=brv[t]-crv[t],bdi=biv[t]-civ[t];
      float t3r=KH*bdi,t3i=-KH*bdr;
      float w1r=twr[p],   w1i=(DIR>0)?twi[p]:-twi[p];
      float w2r=twr[2*p], w2i=(DIR>0)?twi[2*p]:-twi[2*p];
      float y1r=t2r+t3r,y1i=t2i+t3i;
      float y2r=t2r-t3r,y2i=t2i-t3i;
      br[(3*p  )*STR]=y0r;             bi[(3*p  )*STR]=y0i;
      br[(3*p+1)*STR]=y1r*w1r-y1i*w1i; bi[(3*p+1)*STR]=y1r*w1i+y1i*w1r;
      br[(3*p+2)*STR]=y2r*w2r-y2i*w2i; bi[(3*p+2)*STR]=y2r*w2i+y2i*w2r;
    }
    __syncthreads();
  }
  // ---- 7 radix-2 stages ----
  #pragma unroll
  for (int st=0; st<7; st++){
    const int s = 3<<st;
    float ar[3],ai[3],br2[3],bi2[3];
    #pragma unroll
    for (int t=0;t<3;t++){
      int i=u+64*t;
      ar[t]=br[i*STR];        ai[t]=bi[i*STR];
      br2[t]=br[(i+192)*STR]; bi2[t]=bi[(i+192)*STR];
    }
    __syncthreads();
    #pragma unroll
    for (int t=0;t<3;t++){
      int i=u+64*t, p=i/s, tt=p*s;
      float wr=twr[tt], wi=(DIR>0)?twi[tt]:-twi[tt];
      float sur=ar[t]+br2[t],sui=ai[t]+bi2[t];
      float dr=ar[t]-br2[t],di=ai[t]-bi2[t];
      int o=i+tt;
      br[o*STR]=sur;             bi[o*STR]=sui;
      br[(o+s)*STR]=dr*wr-di*wi; bi[(o+s)*STR]=dr*wi+di*wr;
    }
    __syncthreads();
  }
}

// ---------------- K1: fused trig + dot partials -----------------------------
__global__ __launch_bounds__(256) void k_dotA(const void* __restrict__ h1d,
    const void* __restrict__ amp, const void* __restrict__ pph,
    const void* __restrict__ Hm, const void* __restrict__ rg,
    double2* __restrict__ part){
  int wd = blockIdx.x >> 3, ch = blockIdx.x & 7;
  int w = wd >> 4;
  int f = dtflag(rg);
  int m0 = ch << 7;
  __shared__ double sac[128], sas[128];
  int tid = (int)threadIdx.x;
  if (tid < 128){
    double wl = (w==0) ? 6.32e-07 : (w==1 ? 5.5e-07 : 4.5e-07);
    double um2 = (wl*1e6)*(wl*1e6);
    double n_idx = 1.5375 + 0.00829045/um2 - 0.000211046/(um2*um2);
    double coef = (2.0*M_PI/wl)*(n_idx-1.0);
    long mi = m0 + tid;
    double h = ld64(h1d, mi, f);
    double a = ld64(amp, (long)wd*MS2 + mi, f);
    double p = ld64(pph, (long)wd*MS2 + mi, f);
    double s,c; sincos(coef*h + p, &s, &c);
    sac[tid] = a*c; sas[tid] = a*s;
  }
  __syncthreads();
  int r = tid;
  if (r < NG){
    double sr=0.0, si=0.0;
    if (f){
      const double* Hw = (const double*)Hm + ((size_t)w*MS2 + m0)*NG + r;
      #pragma unroll 4
      for (int m=0;m<128;m++){
        double h = Hw[(size_t)m*NG];
        sr += sac[m]*h; si += sas[m]*h;
      }
    } else {
      const float* Hw = (const float*)Hm + ((size_t)w*MS2 + m0)*NG + r;
      #pragma unroll 4
      for (int m=0;m<128;m++){
        double h = (double)Hw[(size_t)m*NG];
        sr += sac[m]*h; si += sas[m]*h;
      }
    }
    part[(size_t)blockIdx.x*NG + r] = make_double2(sr, si);
  }
}

// ---------------- K2: fused dot-reduce + interp + quadrant sum --------------
__global__ __launch_bounds__(256) void k_interp2(const double2* __restrict__ part,
    const void* __restrict__ rg, const void* __restrict__ rs,
    float* __restrict__ q, double* __restrict__ sums_b){
  int wdl = blockIdx.x / 144, blk = blockIdx.x % 144;
  int c = wdl >> 4;
  int pix = blk*256 + (int)threadIdx.x;     // 0..36863
  int f = dtflag(rg);
  __shared__ double v[NG];
  int tid = (int)threadIdx.x;
  if (tid < NG){
    double sr=0.0, si=0.0;
    #pragma unroll
    for (int ch=0; ch<8; ch++){
      double2 pp = part[(size_t)(wdl*8+ch)*NG + tid];
      sr += pp.x; si += pp.y;
    }
    v[tid] = sr*sr + si*si;
  }
  __syncthreads();
  long gbase = (long)c*NG;
  double rho = ld64(rs, (long)c*QPIX + pix, f);
  double g0 = ld64(rg, gbase, f);
  double delta = ld64(rg, gbase+1, f) - g0;
  int i = (int)floor((rho-g0)/delta);
  if (i < 0) i = 0; if (i > 192) i = 192;
  double gi  = ld64(rg, gbase+i,   f);
  double gi1 = ld64(rg, gbase+i+1, f);
  if (i > 0  && rho < gi)  { i--; gi1 = gi; gi = ld64(rg, gbase+i, f); }
  else if (i < 192 && rho > gi1){ i++; gi = gi1; gi1 = ld64(rg, gbase+i+1, f); }
  double gl = ld64(rg, gbase+NG-1, f);
  double val;
  if (rho <= g0)      val = v[0];
  else if (rho >= gl) val = v[NG-1];
  else { double t = (rho-gi)/(gi1-gi); val = v[i] + (v[i+1]-v[i])*t; }
  if (val < 0.0) val = 0.0;
  q[(size_t)wdl*QPIX + pix] = (float)val;
  __shared__ double red[256];
  red[threadIdx.x] = val;
  __syncthreads();
  for (int s=128; s>0; s>>=1){
    if ((int)threadIdx.x < s) red[threadIdx.x] += red[threadIdx.x+s];
    __syncthreads();
  }
  if (threadIdx.x==0) atomicAdd(&sums_b[wdl], red[0]);
}

// ---------------- merged forward ROW pass (single-buffer FFT) ---------------
__global__ __launch_bounds__(256) void k_rows_fwd(
    const float* __restrict__ q, const double* __restrict__ sums,
    float* __restrict__ Rr, const float* __restrict__ img,
    const float* __restrict__ depth, float2* __restrict__ V,
    float2* __restrict__ S){
  __shared__ float br[NSZ*5], bis[NSZ*5];
  __shared__ float twr[NSZ], twi[NSZ];
  init_tws(twr, twi);
  int bi = blockIdx.x;
  int rl = (int)threadIdx.x>>6, u = (int)threadIdx.x&63;
  float *xr=br+rl, *xi=bis+rl;
  if (bi < 48*24){
    int imgi = bi/24, t = bi%24;
    int y0 = t*8 + 2*rl;
    float sc = (float)(1.0/(4.0*sums[imgi]*147456.0));
    const float* q0 = q + ((size_t)imgi*QPIX + (size_t)y0*NHALF);
    const float* q1 = q0 + NHALF;
    #pragma unroll
    for (int k=0;k<6;k++){
      int x = u+64*k;
      int gx = (x<NHALF)? x : (383-x);
      xr[x*5] = q0[gx]*sc;
      xi[x*5] = q1[gx]*sc;
    }
    __syncthreads();
    fftsb<5,1>(xr,xi,u,twr,twi);
    const float PC=0.86602540378443865f, PS=-0.5f;   // e^{-i pi/6}
    float s0,c0; __sincosf((float)M_PI*(float)u/384.0f,&s0,&c0);
    float phr=c0, phi=-s0;                            // e^{-i pi kx/384}
    float* o0 = Rr + ((size_t)imgi*192 + y0)*NSZ;
    float* o1 = o0 + NSZ;
    #pragma unroll
    for (int k=0;k<6;k++){
      int kx = u+64*k;
      int m  = kx ? (384-kx) : 0;
      float Zr=xr[kx*5], Zi=xi[kx*5], Zmr=xr[m*5], Zmi=xi[m*5];
      float Ar=0.5f*(Zr+Zmr), Ai=0.5f*(Zi-Zmi);
      float Br=0.5f*(Zi+Zmi), Bi=-0.5f*(Zr-Zmr);
      o0[kx] = Ar*phr - Ai*phi;
      o1[kx] = Br*phr - Bi*phi;
      float nr=phr*PC-phi*PS, ni=phr*PS+phi*PC; phr=nr; phi=ni;
    }
  } else if (bi < 48*24 + 48*96){
    int i2 = bi - 48*24;
    int im48 = i2/96, grp = i2%96;
    int c = im48>>4, d = im48&15;
    int y = grp*4 + rl;
    const float* i0 = img + (((size_t)0*3+c)*NPIX + (size_t)y*NSZ);
    const float* i1 = img + (((size_t)1*3+c)*NPIX + (size_t)y*NSZ);
    const float* d0 = depth + (size_t)y*NSZ;
    const float* d1 = depth + (size_t)NPIX + (size_t)y*NSZ;
    #pragma unroll
    for (int k=0;k<6;k++){
      int x=u+64*k;
      int ia=(int)floorf(d0[x]*16.f); ia=ia<0?0:(ia>15?15:ia);
      int ib=(int)floorf(d1[x]*16.f); ib=ib<0?0:(ib>15?15:ib);
      xr[x*5] = (ia==d)? i0[x] : 0.f;
      xi[x*5] = (ib==d)? i1[x] : 0.f;
    }
    __syncthreads();
    fftsb<5,1>(xr,xi,u,twr,twi);
    float2* orow = V + ((size_t)im48*NPIX + (size_t)y*NSZ);
    #pragma unroll
    for (int k=0;k<6;k++){ int x=u+64*k; orow[x]=make_float2(xr[x*5],xi[x*5]); }
  } else {
    int i3 = bi - 48*24 - 48*96;
    int d = i3/96, grp = i3%96;            // d in [0,16): batch-packed layered
    int y = grp*4+rl;
    const float* d0 = depth + (size_t)y*NSZ;
    const float* d1 = depth + (size_t)NPIX + (size_t)y*NSZ;
    #pragma unroll
    for (int k=0;k<6;k++){
      int x=u+64*k;
      int ia=(int)floorf(d0[x]*16.f); ia=ia<0?0:(ia>15?15:ia);
      int ib=(int)floorf(d1[x]*16.f); ib=ib<0?0:(ib>15?15:ib);
      xr[x*5]=(ia==d)?1.f:0.f;
      xi[x*5]=(ib==d)?1.f:0.f;
    }
    __syncthreads();
    fftsb<5,1>(xr,xi,u,twr,twi);
    float2* orow = S + ((size_t)d*NPIX + (size_t)y*NSZ);
    #pragma unroll
    for (int k=0;k<6;k++){ int x=u+64*k; orow[x]=make_float2(xr[x*5],xi[x*5]); }
  }
}

// ---------------- merged col pass: F-build (real) + S forward (16 imgs) -----
__global__ __launch_bounds__(512) void k_colsFS(const float* __restrict__ Rr,
    float* __restrict__ Rc, float2* __restrict__ S){
  __shared__ float br[NSZ*9], bis[NSZ*9];
  __shared__ float twr[NSZ], twi[NSZ];
  init_tws(twr,twi);
  int bi = blockIdx.x;
  if (bi < 1152){
    int imgi = bi/24, cg = bi%24;
    int j16 = (int)threadIdx.x&15, r0 = (int)threadIdx.x>>4;   // r0 in [0,32)
    int uu = j16>>1;
    const float* rbase = Rr + (size_t)imgi*192*NSZ + cg*16 + j16;
    #pragma unroll
    for (int k=0;k<12;k++){
      int y = r0 + 32*k;
      int gy = (y<NHALF)? y : (383-y);
      float v = rbase[(size_t)gy*NSZ];
      if (j16&1) bis[y*9+uu]=v; else br[y*9+uu]=v;
    }
    __syncthreads();
    int cc = (int)threadIdx.x>>6, u = (int)threadIdx.x&63;
    fftsb<9,1>(br+cc,bis+cc,u,twr,twi);
    const float PC=0.96592582628906829f, PS=-0.25881904510252076f; // e^{-i pi/12}
    float s0,c0; __sincosf((float)M_PI*(float)r0/384.f,&s0,&c0);
    float phr=c0, phi=-s0;
    float* ob = Rc + (size_t)imgi*NPIX + cg*16 + j16;
    #pragma unroll
    for (int k=0;k<12;k++){
      int ky=r0+32*k;
      int m = ky ? (384-ky) : 0;
      float Zr=br[ky*9+uu], Zi=bis[ky*9+uu], Zmr=br[m*9+uu], Zmi=bis[m*9+uu];
      float Cr,Ci;
      if (j16&1){ Cr=0.5f*(Zi+Zmi); Ci=-0.5f*(Zr-Zmr); }
      else      { Cr=0.5f*(Zr+Zmr); Ci= 0.5f*(Zi-Zmi); }
      ob[(size_t)ky*NSZ] = Cr*phr - Ci*phi;
      float nr=phr*PC-phi*PS, ni=phr*PS+phi*PC; phr=nr; phi=ni;
    }
  } else {
    int i2 = bi - 1152;
    int imgi = i2/48, cg = i2%48;          // imgi in [0,16)
    size_t boff = (size_t)imgi*NPIX + (size_t)cg*8;
    int j = (int)threadIdx.x&7, r0 = (int)threadIdx.x>>3;
    #pragma unroll
    for (int k=0;k<6;k++){
      int r=r0+64*k;
      float2 v = S[boff + (size_t)r*NSZ + j];
      br[r*9+j]=v.x; bis[r*9+j]=v.y;
    }
    __syncthreads();
    int cc=(int)threadIdx.x>>6, u=(int)threadIdx.x&63;
    fftsb<9,1>(br+cc,bis+cc,u,twr,twi);
    #pragma unroll
    for (int k=0;k<6;k++){
      int r=r0+64*k;
      S[boff+(size_t)r*NSZ+j] = make_float2(br[r*9+j], bis[r*9+j]);
    }
  }
}

// ---------------- merged: fused V-convolution + mulinv, 16-col tiles --------
// 1024 thr = 16 FFT units; LDS stride 17 (odd -> 2-way conflicts only).
// bi < nf (=48*24): fwd cols + mul + inv cols on V (16 cols), in place.
// else: mulinv over (c,d,cg16): L[c*ND+d] = icolFFT(S[d]*F[c,d]).
// NOTE: no min-waves clamp -- (1024,8) forced VGPR=32 and spilled ~184MB
// of scratch writes (round-15 counters). Let the allocator pick (~56).
__global__ __launch_bounds__(1024) void k_FM(float2* __restrict__ V,
    const float* __restrict__ Rc, const float2* __restrict__ S,
    float2* __restrict__ L, int nf){
  __shared__ float br[NSZ*17], bis[NSZ*17];
  __shared__ float twr[NSZ], twi[NSZ];
  init_tws(twr,twi);
  const float PC=0.86602540378443865f, PS=0.5f;   // e^{+i pi/6}
  int bi = blockIdx.x;
  int tid = (int)threadIdx.x;
  int j = tid&15, r0 = tid>>4;            // r0 in [0,64)
  int unit = tid>>6, u = tid&63;          // 16 FFT units
  if (bi < nf){
    int imgi = bi/24, cg = bi%24;
    size_t boff = (size_t)imgi*NPIX + (size_t)cg*16;
    #pragma unroll
    for (int k=0;k<6;k++){
      int r=r0+64*k;
      float2 v = V[boff + (size_t)r*NSZ + j];
      br[r*17+j]=v.x; bis[r*17+j]=v.y;
    }
    __syncthreads();
    fftsb<17,1>(br+unit,bis+unit,u,twr,twi);
    int kx = cg*16+j;
    float s0,c0; __sincosf((float)M_PI*(float)(kx+r0)/384.f,&s0,&c0);
    float phr=c0, phi=s0;
    const float* rb = Rc + (size_t)imgi*NPIX + kx;
    #pragma unroll
    for (int k=0;k<6;k++){
      int r=r0+64*k;
      float R = rb[(size_t)r*NSZ];
      float fr=R*phr, fi=R*phi;
      float brv=br[r*17+j], biv=bis[r*17+j];
      br[r*17+j]  = brv*fr - biv*fi;
      bis[r*17+j] = brv*fi + biv*fr;
      float nr=phr*PC-phi*PS, ni=phr*PS+phi*PC; phr=nr; phi=ni;
    }
    __syncthreads();
    fftsb<17,-1>(br+unit,bis+unit,u,twr,twi);
    #pragma unroll
    for (int k=0;k<6;k++){
      int r=r0+64*k;
      V[boff+(size_t)r*NSZ+j] = make_float2(br[r*17+j], bis[r*17+j]);
    }
  } else {
    int t = bi - nf;
    int cg = t%24, d=(t/24)&15, c=t/(24*16);   // c in [0,3)
    const float2* src = S  + ((size_t)d*NPIX + (size_t)cg*16);
    const float*  rb  = Rc + ((size_t)(c*ND+d)*NPIX + cg*16);
    float2*       dst = L  + ((size_t)(c*ND+d)*NPIX + (size_t)cg*16);
    int kx = cg*16+j;
    float s0,c0; __sincosf((float)M_PI*(float)(kx+r0)/384.f,&s0,&c0);
    float phr=c0, phi=s0;
    #pragma unroll
    for (int k=0;k<6;k++){
      int r=r0+64*k;
      float2 v = src[(size_t)r*NSZ + j];
      float R = rb[(size_t)r*NSZ + j];
      float fr=R*phr, fi=R*phi;
      br[r*17+j]  = v.x*fr - v.y*fi;
      bis[r*17+j] = v.x*fi + v.y*fr;
      float nr=phr*PC-phi*PS, ni=phr*PS+phi*PC; phr=nr; phi=ni;
    }
    __syncthreads();
    fftsb<17,-1>(br+unit,bis+unit,u,twr,twi);
    #pragma unroll
    for (int k=0;k<6;k++){
      int r=r0+64*k;
      dst[(size_t)r*NSZ+j] = make_float2(br[r*17+j], bis[r*17+j]);
    }
  }
}

// ---------------- inverse row FFT in place: V (48 imgs) + L (48 imgs) -------
// grid 9216; 4 rows/block; single-buffer FFT -> 18.4KB LDS, 8 blocks/CU.
__global__ __launch_bounds__(256) void k_rowsinv(float2* __restrict__ V,
    float2* __restrict__ L){
  __shared__ float br[NSZ*5], bis[NSZ*5];
  __shared__ float twr[NSZ], twi[NSZ];
  init_tws(twr,twi);
  int bi = blockIdx.x;
  float2* base; int ri;
  if (bi < 4608){ base = V; ri = bi; } else { base = L; ri = bi - 4608; }
  int rl=(int)threadIdx.x>>6, u=(int)threadIdx.x&63;
  float *xr=br+rl,*xi=bis+rl;
  float2* row = base + ((size_t)ri*4 + rl)*NSZ;
  #pragma unroll
  for (int k=0;k<6;k++){ int x=u+64*k; float2 v=row[x]; xr[x*5]=v.x; xi[x*5]=v.y; }
  __syncthreads();
  fftsb<5,-1>(xr,xi,u,twr,twi);
  #pragma unroll
  for (int k=0;k<6;k++){ int x=u+64*k; row[x]=make_float2(xr[x*5],xi[x*5]); }
}

// ---------------- streaming occlusion compositing (no FFT) ------------------
// grid 864 x 256; 2 pixels/thread via float4. L,V SPATIAL (c*ND+d):
// re/im = batch0/batch1. DESCENDING d + Horner (round-11 verified math).
__global__ __launch_bounds__(256) void k_combine(const float2* __restrict__ L,
    const float2* __restrict__ V, float* __restrict__ out){
  int t = blockIdx.x*256 + (int)threadIdx.x;   // < 3*NPIX/2
  int c = t / (NPIX/2);
  int pp = t - c*(NPIX/2);                     // pixel-pair index
  size_t base = (size_t)(c*ND)*NPIX + (size_t)pp*2;
  float A0a=0.f,C0a=0.f,A1a=0.f,C1a=0.f;
  float A0b=0.f,C0b=0.f,A1b=0.f,C1b=0.f;
  for (int d=ND-1; d>=0; --d){
    float4 l = *(const float4*)(L + base + (size_t)d*NPIX);
    float4 v = *(const float4*)(V + base + (size_t)d*NPIX);
    A0a += l.x; A1a += l.y; A0b += l.z; A1b += l.w;
    float ic0a=1.f/(A0a+EPSV), ic1a=1.f/(A1a+EPSV);
    float ic0b=1.f/(A0b+EPSV), ic1b=1.f/(A1b+EPSV);
    C0a = v.x*ic0a + (1.f - l.x*ic0a)*C0a;
    C1a = v.y*ic1a + (1.f - l.y*ic1a)*C1a;
    C0b = v.z*ic0b + (1.f - l.z*ic0b)*C0b;
    C1b = v.w*ic1b + (1.f - l.w*ic1b)*C1b;
  }
  size_t o0 = (size_t)(0*3 + c)*NPIX + (size_t)pp*2;
  size_t o1 = (size_t)(1*3 + c)*NPIX + (size_t)pp*2;
  out[o0]   = C0a; out[o0+1] = C0b;
  out[o1]   = C1a; out[o1+1] = C1b;
}

extern "C" void kernel_launch(void* const* d_in, const int* in_sizes, int n_in,
                              void* d_out, int out_size, void* d_ws, size_t ws_size,
                              hipStream_t stream){
  const float* img   = (const float*)d_in[0];   // (2,3,384,384) f32
  const float* depth = (const float*)d_in[1];   // (2,1,384,384) f32
  const void*  h1d   = d_in[2];                 // (1024,)
  const void*  amp   = d_in[3];                 // (3,16,1024)
  const void*  pph   = d_in[4];                 // (3,16,1024)
  const void*  Hm    = d_in[5];                 // (3,1024,194)
  const void*  rg    = d_in[6];                 // (3,194)
  const void*  rs    = d_in[7];                 // (3,192,192)
  float* out = (float*)d_out;
  (void)in_sizes; (void)n_in; (void)out_size;

  char* ws = (char*)d_ws;
  size_t off = 0;
  auto take = [&](size_t b)->char*{ char* p = ws + off; off += (b + 255) & ~(size_t)255; return p; };
  double*  sums = (double*) take((size_t)48*8);
  double2* part = (double2*)take((size_t)48*8*NG*16);     //  1.19 MB
  float*   q    = (float*)  take((size_t)48*QPIX*4);      //  7.08 MB
  float*   Rr   = (float*)  take((size_t)48*192*NSZ*4);   // 14.16 MB
  float*   Rc   = (float*)  take((size_t)48*NPIX*4);      // 28.31 MB
  float2*  V    = (float2*) take((size_t)48*NPIX*8);      // 56.62 MB
  float2*  S    = (float2*) take((size_t)16*NPIX*8);      // 18.87 MB
  float2*  L    = (float2*) take((size_t)48*NPIX*8);      // 56.62 MB
  if (ws_size < off) return;   // ~183 MB; clean absmax failure, not a fault

  hipMemsetAsync(sums, 0, 48*8, stream);
  k_dotA<<<48*8, 256, 0, stream>>>(h1d, amp, pph, Hm, rg, part);
  k_interp2<<<48*144, 256, 0, stream>>>(part, rg, rs, q, sums);
  k_rows_fwd<<<48*24 + 48*96 + 16*96, 256, 0, stream>>>(q, sums, Rr, img, depth, V, S);
  k_colsFS<<<1152 + 16*48, 512, 0, stream>>>(Rr, Rc, S);
  k_FM<<<48*24 + 3*16*24, 1024, 0, stream>>>(V, Rc, S, L, 48*24);
  k_rowsinv<<<9216, 256, 0, stream>>>(V, L);
  k_combine<<<864, 256, 0, stream>>>(L, V, out);
}

// Round 17
// 310.742 us; speedup vs baseline: 1.0807x; 1.0505x over previous
//
#include <hip/hip_runtime.h>
#include <math.h>

#define ND 16
#define NSZ 384
#define NHALF 192
#define NPIX 147456    // 384*384
#define QPIX 36864     // 192*192
#define MS2 1024
#define NG 194
#define EPSV 0.001f

// load element i of a buffer that is f64 (flag=1) or f32 (flag=0)
__device__ __forceinline__ double ld64(const void* p, long i, int f){
  return f ? ((const double*)p)[i] : (double)((const float*)p)[i];
}
// dtype detect inline
__device__ __forceinline__ int dtflag(const void* rg){
  double d = ((const double*)rg)[1];
  return (fabs(d) < 1.0e9) ? 1 : 0;
}

// ---------------- twiddles (SoA): twr[j]=cos, twi[j]=-sin (e^{-2pi i j/384})
__device__ __forceinline__ void init_tws(float* twr, float* twi){
  for (int j=(int)threadIdx.x; j<NSZ; j+=(int)blockDim.x){
    double s,c; sincos((2.0*M_PI/384.0)*(double)j, &s, &c);
    twr[j]=(float)c; twi[j]=(float)(-s);
  }
}

// ------- SINGLE-BUFFER SoA Stockham FFT, N=384=3*2^7, 64 thr/transform ------
template<int STR,int DIR>
__device__ __forceinline__ void fftsb(float* br,float* bi,int u,
                                      const float* twr,const float* twi){
  const float KH = (DIR>0)?0.86602540378443865f:-0.86602540378443865f;
  {
    float ar[2],ai[2],brv[2],biv[2],crv[2],civ[2];
    #pragma unroll
    for (int t=0;t<2;t++){
      int p=u+64*t;
      ar[t]=br[p*STR];        ai[t]=bi[p*STR];
      brv[t]=br[(p+128)*STR]; biv[t]=bi[(p+128)*STR];
      crv[t]=br[(p+256)*STR]; civ[t]=bi[(p+256)*STR];
    }
    __syncthreads();
    #pragma unroll
    for (int t=0;t<2;t++){
      int p=u+64*t;
      float t1r=brv[t]+crv[t],t1i=biv[t]+civ[t];
      float y0r=ar[t]+t1r,y0i=ai[t]+t1i;
      float t2r=ar[t]-0.5f*t1r,t2i=ai[t]-0.5f*t1i;
      float bdr=brv[t]-crv[t],bdi=biv[t]-civ[t];
      float t3r=KH*bdi,t3i=-KH*bdr;
      float w1r=twr[p],   w1i=(DIR>0)?twi[p]:-twi[p];
      float w2r=twr[2*p], w2i=(DIR>0)?twi[2*p]:-twi[2*p];
      float y1r=t2r+t3r,y1i=t2i+t3i;
      float y2r=t2r-t3r,y2i=t2i-t3i;
      br[(3*p  )*STR]=y0r;             bi[(3*p  )*STR]=y0i;
      br[(3*p+1)*STR]=y1r*w1r-y1i*w1i; bi[(3*p+1)*STR]=y1r*w1i+y1i*w1r;
      br[(3*p+2)*STR]=y2r*w2r-y2i*w2i; bi[(3*p+2)*STR]=y2r*w2i+y2i*w2r;
    }
    __syncthreads();
  }
  #pragma unroll
  for (int st=0; st<7; st++){
    const int s = 3<<st;
    float ar[3],ai[3],br2[3],bi2[3];
    #pragma unroll
    for (int t=0;t<3;t++){
      int i=u+64*t;
      ar[t]=br[i*STR];        ai[t]=bi[i*STR];
      br2[t]=br[(i+192)*STR]; bi2[t]=bi[(i+192)*STR];
    }
    __syncthreads();
    #pragma unroll
    for (int t=0;t<3;t++){
      int i=u+64*t, p=i/s, tt=p*s;
      float wr=twr[tt], wi=(DIR>0)?twi[tt]:-twi[tt];
      float sur=ar[t]+br2[t],sui=ai[t]+bi2[t];
      float dr=ar[t]-br2[t],di=ai[t]-bi2[t];
      int o=i+tt;
      br[o*STR]=sur;             bi[o*STR]=sui;
      br[(o+s)*STR]=dr*wr-di*wi; bi[(o+s)*STR]=dr*wi+di*wr;
    }
    __syncthreads();
  }
}

// ------- DOUBLE-BUFFER SoA Stockham FFT (ping-pong), result back in x -------
// Fewer barriers (8) than fftsb (16); best measured form for k_FM (r12: 110us).
template<int STR,int DIR>
__device__ __forceinline__ void fft384s(float* xr,float* xi,float* yr,float* yi,
                                        int u,const float* twr,const float* twi){
  const float KH = (DIR>0)?0.86602540378443865f:-0.86602540378443865f;
  float *Xr=xr,*Xi=xi,*Yr=yr,*Yi=yi;
  #pragma unroll
  for (int i0=0;i0<128;i0+=64){
    int p=i0+u;
    float ar=Xr[p*STR],ai=Xi[p*STR];
    float br=Xr[(p+128)*STR],bi=Xi[(p+128)*STR];
    float cr=Xr[(p+256)*STR],ci=Xi[(p+256)*STR];
    float t1r=br+cr,t1i=bi+ci;
    float y0r=ar+t1r,y0i=ai+t1i;
    float t2r=ar-0.5f*t1r,t2i=ai-0.5f*t1i;
    float bdr=br-cr,bdi=bi-ci;
    float t3r=KH*bdi,t3i=-KH*bdr;
    float w1r=twr[p],     w1i=(DIR>0)?twi[p]:-twi[p];
    float w2r=twr[2*p],   w2i=(DIR>0)?twi[2*p]:-twi[2*p];
    float y1r=t2r+t3r,y1i=t2i+t3i;
    float y2r=t2r-t3r,y2i=t2i-t3i;
    Yr[(3*p  )*STR]=y0r;             Yi[(3*p  )*STR]=y0i;
    Yr[(3*p+1)*STR]=y1r*w1r-y1i*w1i; Yi[(3*p+1)*STR]=y1r*w1i+y1i*w1r;
    Yr[(3*p+2)*STR]=y2r*w2r-y2i*w2i; Yi[(3*p+2)*STR]=y2r*w2i+y2i*w2r;
  }
  __syncthreads();
  { float*t; t=Xr;Xr=Yr;Yr=t; t=Xi;Xi=Yi;Yi=t; }
  #pragma unroll
  for (int st=0; st<7; st++){
    const int s = 3<<st;
    #pragma unroll
    for (int i0=0;i0<192;i0+=64){
      int i=i0+u, p=i/s, t=p*s;
      float ar=Xr[i*STR],ai=Xi[i*STR];
      float br=Xr[(i+192)*STR],bi=Xi[(i+192)*STR];
      float wr=twr[t], wi=(DIR>0)?twi[t]:-twi[t];
      float sur=ar+br,sui=ai+bi;
      float dr=ar-br,di=ai-bi;
      int o=i+t;
      Yr[o*STR]=sur;             Yi[o*STR]=sui;
      Yr[(o+s)*STR]=dr*wr-di*wi; Yi[(o+s)*STR]=dr*wi+di*wr;
    }
    __syncthreads();
    { float*t2; t2=Xr;Xr=Yr;Yr=t2; t2=Xi;Xi=Yi;Yi=t2; }
  }
}

// ---------------- K1: fused trig + dot partials -----------------------------
__global__ __launch_bounds__(256) void k_dotA(const void* __restrict__ h1d,
    const void* __restrict__ amp, const void* __restrict__ pph,
    const void* __restrict__ Hm, const void* __restrict__ rg,
    double2* __restrict__ part){
  int wd = blockIdx.x >> 3, ch = blockIdx.x & 7;
  int w = wd >> 4;
  int f = dtflag(rg);
  int m0 = ch << 7;
  __shared__ double sac[128], sas[128];
  int tid = (int)threadIdx.x;
  if (tid < 128){
    double wl = (w==0) ? 6.32e-07 : (w==1 ? 5.5e-07 : 4.5e-07);
    double um2 = (wl*1e6)*(wl*1e6);
    double n_idx = 1.5375 + 0.00829045/um2 - 0.000211046/(um2*um2);
    double coef = (2.0*M_PI/wl)*(n_idx-1.0);
    long mi = m0 + tid;
    double h = ld64(h1d, mi, f);
    double a = ld64(amp, (long)wd*MS2 + mi, f);
    double p = ld64(pph, (long)wd*MS2 + mi, f);
    double s,c; sincos(coef*h + p, &s, &c);
    sac[tid] = a*c; sas[tid] = a*s;
  }
  __syncthreads();
  int r = tid;
  if (r < NG){
    double sr=0.0, si=0.0;
    if (f){
      const double* Hw = (const double*)Hm + ((size_t)w*MS2 + m0)*NG + r;
      #pragma unroll 4
      for (int m=0;m<128;m++){
        double h = Hw[(size_t)m*NG];
        sr += sac[m]*h; si += sas[m]*h;
      }
    } else {
      const float* Hw = (const float*)Hm + ((size_t)w*MS2 + m0)*NG + r;
      #pragma unroll 4
      for (int m=0;m<128;m++){
        double h = (double)Hw[(size_t)m*NG];
        sr += sac[m]*h; si += sas[m]*h;
      }
    }
    part[(size_t)blockIdx.x*NG + r] = make_double2(sr, si);
  }
}

// ---------------- K2: fused dot-reduce + interp + quadrant sum --------------
__global__ __launch_bounds__(256) void k_interp2(const double2* __restrict__ part,
    const void* __restrict__ rg, const void* __restrict__ rs,
    float* __restrict__ q, double* __restrict__ sums_b){
  int wdl = blockIdx.x / 144, blk = blockIdx.x % 144;
  int c = wdl >> 4;
  int pix = blk*256 + (int)threadIdx.x;     // 0..36863
  int f = dtflag(rg);
  __shared__ double v[NG];
  int tid = (int)threadIdx.x;
  if (tid < NG){
    double sr=0.0, si=0.0;
    #pragma unroll
    for (int ch=0; ch<8; ch++){
      double2 pp = part[(size_t)(wdl*8+ch)*NG + tid];
      sr += pp.x; si += pp.y;
    }
    v[tid] = sr*sr + si*si;
  }
  __syncthreads();
  long gbase = (long)c*NG;
  double rho = ld64(rs, (long)c*QPIX + pix, f);
  double g0 = ld64(rg, gbase, f);
  double delta = ld64(rg, gbase+1, f) - g0;
  int i = (int)floor((rho-g0)/delta);
  if (i < 0) i = 0; if (i > 192) i = 192;
  double gi  = ld64(rg, gbase+i,   f);
  double gi1 = ld64(rg, gbase+i+1, f);
  if (i > 0  && rho < gi)  { i--; gi1 = gi; gi = ld64(rg, gbase+i, f); }
  else if (i < 192 && rho > gi1){ i++; gi = gi1; gi1 = ld64(rg, gbase+i+1, f); }
  double gl = ld64(rg, gbase+NG-1, f);
  double val;
  if (rho <= g0)      val = v[0];
  else if (rho >= gl) val = v[NG-1];
  else { double t = (rho-gi)/(gi1-gi); val = v[i] + (v[i+1]-v[i])*t; }
  if (val < 0.0) val = 0.0;
  q[(size_t)wdl*QPIX + pix] = (float)val;
  __shared__ double red[256];
  red[threadIdx.x] = val;
  __syncthreads();
  for (int s=128; s>0; s>>=1){
    if ((int)threadIdx.x < s) red[threadIdx.x] += red[threadIdx.x+s];
    __syncthreads();
  }
  if (threadIdx.x==0) atomicAdd(&sums_b[wdl], red[0]);
}

// ---------------- merged forward ROW pass (single-buffer FFT) ---------------
__global__ __launch_bounds__(256) void k_rows_fwd(
    const float* __restrict__ q, const double* __restrict__ sums,
    float* __restrict__ Rr, const float* __restrict__ img,
    const float* __restrict__ depth, float2* __restrict__ V,
    float2* __restrict__ S){
  __shared__ float br[NSZ*5], bis[NSZ*5];
  __shared__ float twr[NSZ], twi[NSZ];
  init_tws(twr, twi);
  int bi = blockIdx.x;
  int rl = (int)threadIdx.x>>6, u = (int)threadIdx.x&63;
  float *xr=br+rl, *xi=bis+rl;
  if (bi < 48*24){
    int imgi = bi/24, t = bi%24;
    int y0 = t*8 + 2*rl;
    float sc = (float)(1.0/(4.0*sums[imgi]*147456.0));
    const float* q0 = q + ((size_t)imgi*QPIX + (size_t)y0*NHALF);
    const float* q1 = q0 + NHALF;
    #pragma unroll
    for (int k=0;k<6;k++){
      int x = u+64*k;
      int gx = (x<NHALF)? x : (383-x);
      xr[x*5] = q0[gx]*sc;
      xi[x*5] = q1[gx]*sc;
    }
    __syncthreads();
    fftsb<5,1>(xr,xi,u,twr,twi);
    const float PC=0.86602540378443865f, PS=-0.5f;   // e^{-i pi/6}
    float s0,c0; __sincosf((float)M_PI*(float)u/384.0f,&s0,&c0);
    float phr=c0, phi=-s0;                            // e^{-i pi kx/384}
    float* o0 = Rr + ((size_t)imgi*192 + y0)*NSZ;
    float* o1 = o0 + NSZ;
    #pragma unroll
    for (int k=0;k<6;k++){
      int kx = u+64*k;
      int m  = kx ? (384-kx) : 0;
      float Zr=xr[kx*5], Zi=xi[kx*5], Zmr=xr[m*5], Zmi=xi[m*5];
      float Ar=0.5f*(Zr+Zmr), Ai=0.5f*(Zi-Zmi);
      float Br=0.5f*(Zi+Zmi), Bi=-0.5f*(Zr-Zmr);
      o0[kx] = Ar*phr - Ai*phi;
      o1[kx] = Br*phr - Bi*phi;
      float nr=phr*PC-phi*PS, ni=phr*PS+phi*PC; phr=nr; phi=ni;
    }
  } else if (bi < 48*24 + 48*96){
    int i2 = bi - 48*24;
    int im48 = i2/96, grp = i2%96;
    int c = im48>>4, d = im48&15;
    int y = grp*4 + rl;
    const float* i0 = img + (((size_t)0*3+c)*NPIX + (size_t)y*NSZ);
    const float* i1 = img + (((size_t)1*3+c)*NPIX + (size_t)y*NSZ);
    const float* d0 = depth + (size_t)y*NSZ;
    const float* d1 = depth + (size_t)NPIX + (size_t)y*NSZ;
    #pragma unroll
    for (int k=0;k<6;k++){
      int x=u+64*k;
      int ia=(int)floorf(d0[x]*16.f); ia=ia<0?0:(ia>15?15:ia);
      int ib=(int)floorf(d1[x]*16.f); ib=ib<0?0:(ib>15?15:ib);
      xr[x*5] = (ia==d)? i0[x] : 0.f;
      xi[x*5] = (ib==d)? i1[x] : 0.f;
    }
    __syncthreads();
    fftsb<5,1>(xr,xi,u,twr,twi);
    float2* orow = V + ((size_t)im48*NPIX + (size_t)y*NSZ);
    #pragma unroll
    for (int k=0;k<6;k++){ int x=u+64*k; orow[x]=make_float2(xr[x*5],xi[x*5]); }
  } else {
    int i3 = bi - 48*24 - 48*96;
    int d = i3/96, grp = i3%96;            // d in [0,16): batch-packed layered
    int y = grp*4+rl;
    const float* d0 = depth + (size_t)y*NSZ;
    const float* d1 = depth + (size_t)NPIX + (size_t)y*NSZ;
    #pragma unroll
    for (int k=0;k<6;k++){
      int x=u+64*k;
      int ia=(int)floorf(d0[x]*16.f); ia=ia<0?0:(ia>15?15:ia);
      int ib=(int)floorf(d1[x]*16.f); ib=ib<0?0:(ib>15?15:ib);
      xr[x*5]=(ia==d)?1.f:0.f;
      xi[x*5]=(ib==d)?1.f:0.f;
    }
    __syncthreads();
    fftsb<5,1>(xr,xi,u,twr,twi);
    float2* orow = S + ((size_t)d*NPIX + (size_t)y*NSZ);
    #pragma unroll
    for (int k=0;k<6;k++){ int x=u+64*k; orow[x]=make_float2(xr[x*5],xi[x*5]); }
  }
}

// ---------------- merged col pass: F-build (real) + S forward (16 imgs) -----
__global__ __launch_bounds__(512) void k_colsFS(const float* __restrict__ Rr,
    float* __restrict__ Rc, float2* __restrict__ S){
  __shared__ float br[NSZ*9], bis[NSZ*9];
  __shared__ float twr[NSZ], twi[NSZ];
  init_tws(twr,twi);
  int bi = blockIdx.x;
  if (bi < 1152){
    int imgi = bi/24, cg = bi%24;
    int j16 = (int)threadIdx.x&15, r0 = (int)threadIdx.x>>4;   // r0 in [0,32)
    int uu = j16>>1;
    const float* rbase = Rr + (size_t)imgi*192*NSZ + cg*16 + j16;
    #pragma unroll
    for (int k=0;k<12;k++){
      int y = r0 + 32*k;
      int gy = (y<NHALF)? y : (383-y);
      float v = rbase[(size_t)gy*NSZ];
      if (j16&1) bis[y*9+uu]=v; else br[y*9+uu]=v;
    }
    __syncthreads();
    int cc = (int)threadIdx.x>>6, u = (int)threadIdx.x&63;
    fftsb<9,1>(br+cc,bis+cc,u,twr,twi);
    const float PC=0.96592582628906829f, PS=-0.25881904510252076f; // e^{-i pi/12}
    float s0,c0; __sincosf((float)M_PI*(float)r0/384.f,&s0,&c0);
    float phr=c0, phi=-s0;
    float* ob = Rc + (size_t)imgi*NPIX + cg*16 + j16;
    #pragma unroll
    for (int k=0;k<12;k++){
      int ky=r0+32*k;
      int m = ky ? (384-ky) : 0;
      float Zr=br[ky*9+uu], Zi=bis[ky*9+uu], Zmr=br[m*9+uu], Zmi=bis[m*9+uu];
      float Cr,Ci;
      if (j16&1){ Cr=0.5f*(Zi+Zmi); Ci=-0.5f*(Zr-Zmr); }
      else      { Cr=0.5f*(Zr+Zmr); Ci= 0.5f*(Zi-Zmi); }
      ob[(size_t)ky*NSZ] = Cr*phr - Ci*phi;
      float nr=phr*PC-phi*PS, ni=phr*PS+phi*PC; phr=nr; phi=ni;
    }
  } else {
    int i2 = bi - 1152;
    int imgi = i2/48, cg = i2%48;          // imgi in [0,16)
    size_t boff = (size_t)imgi*NPIX + (size_t)cg*8;
    int j = (int)threadIdx.x&7, r0 = (int)threadIdx.x>>3;
    #pragma unroll
    for (int k=0;k<6;k++){
      int r=r0+64*k;
      float2 v = S[boff + (size_t)r*NSZ + j];
      br[r*9+j]=v.x; bis[r*9+j]=v.y;
    }
    __syncthreads();
    int cc=(int)threadIdx.x>>6, u=(int)threadIdx.x&63;
    fftsb<9,1>(br+cc,bis+cc,u,twr,twi);
    #pragma unroll
    for (int k=0;k<6;k++){
      int r=r0+64*k;
      S[boff+(size_t)r*NSZ+j] = make_float2(br[r*9+j], bis[r*9+j]);
    }
  }
}

// ---------------- merged: fused V-convolution + mulinv (S*F -> L) -----------
// ROUND-12 FORM (best measured: 110us): 512 thr, 8-col tiles, double-buffer.
// bi < nf (=48*48): fwd cols + mul + inv cols on V, in place (x-spectral out).
// else: mulinv over (c,d,cg): L[c*ND+d] = icolFFT(S[d]*F[c,d]) (both batches).
__global__ __launch_bounds__(512) void k_FM(float2* __restrict__ V,
    const float* __restrict__ Rc, const float2* __restrict__ S,
    float2* __restrict__ L, int nf){
  __shared__ float b0r[NSZ*9], b0i[NSZ*9], b1r[NSZ*9], b1i[NSZ*9];
  __shared__ float twr[NSZ], twi[NSZ];
  init_tws(twr,twi);
  const float PC=0.86602540378443865f, PS=0.5f;   // e^{+i pi/6}
  int bi = blockIdx.x;
  int j = (int)threadIdx.x&7, r0 = (int)threadIdx.x>>3;
  int cc=(int)threadIdx.x>>6, u=(int)threadIdx.x&63;
  if (bi < nf){
    int imgi = bi/48, cg = bi%48;
    size_t boff = (size_t)imgi*NPIX + (size_t)cg*8;
    #pragma unroll
    for (int k=0;k<6;k++){
      int r=r0+64*k;
      float2 v = V[boff + (size_t)r*NSZ + j];
      b0r[r*9+j]=v.x; b0i[r*9+j]=v.y;
    }
    __syncthreads();
    fft384s<9,1>(b0r+cc,b0i+cc,b1r+cc,b1i+cc,u,twr,twi);
    int kx = cg*8+j;
    float s0,c0; __sincosf((float)M_PI*(float)(kx+r0)/384.f,&s0,&c0);
    float phr=c0, phi=s0;
    const float* rb = Rc + (size_t)imgi*NPIX + kx;
    #pragma unroll
    for (int k=0;k<6;k++){
      int r=r0+64*k;
      float R = rb[(size_t)r*NSZ];
      float fr=R*phr, fi=R*phi;
      float brv=b0r[r*9+j], biv=b0i[r*9+j];
      b0r[r*9+j] = brv*fr - biv*fi;
      b0i[r*9+j] = brv*fi + biv*fr;
      float nr=phr*PC-phi*PS, ni=phr*PS+phi*PC; phr=nr; phi=ni;
    }
    __syncthreads();
    fft384s<9,-1>(b0r+cc,b0i+cc,b1r+cc,b1i+cc,u,twr,twi);
    #pragma unroll
    for (int k=0;k<6;k++){
      int r=r0+64*k;
      V[boff+(size_t)r*NSZ+j] = make_float2(b0r[r*9+j], b0i[r*9+j]);
    }
  } else {
    int t = bi - nf;
    int cg = t%48, d=(t/48)&15, c=t/(48*16);   // c in [0,3)
    const float2* src = S  + ((size_t)d*NPIX + (size_t)cg*8);
    const float*  rb  = Rc + ((size_t)(c*ND+d)*NPIX + cg*8);
    float2*       dst = L  + ((size_t)(c*ND+d)*NPIX + (size_t)cg*8);
    int kx = cg*8+j;
    float s0,c0; __sincosf((float)M_PI*(float)(kx+r0)/384.f,&s0,&c0);
    float phr=c0, phi=s0;
    #pragma unroll
    for (int k=0;k<6;k++){
      int r=r0+64*k;
      float2 v = src[(size_t)r*NSZ + j];
      float R = rb[(size_t)r*NSZ + j];
      float fr=R*phr, fi=R*phi;
      b0r[r*9+j] = v.x*fr - v.y*fi;
      b0i[r*9+j] = v.x*fi + v.y*fr;
      float nr=phr*PC-phi*PS, ni=phr*PS+phi*PC; phr=nr; phi=ni;
    }
    __syncthreads();
    fft384s<9,-1>(b0r+cc,b0i+cc,b1r+cc,b1i+cc,u,twr,twi);
    #pragma unroll
    for (int k=0;k<6;k++){
      int r=r0+64*k;
      dst[(size_t)r*NSZ+j] = make_float2(b0r[r*9+j], b0i[r*9+j]);
    }
  }
}

// ---------------- inverse row FFT in place: V (48 imgs) + L (48 imgs) -------
__global__ __launch_bounds__(256) void k_rowsinv(float2* __restrict__ V,
    float2* __restrict__ L){
  __shared__ float br[NSZ*5], bis[NSZ*5];
  __shared__ float twr[NSZ], twi[NSZ];
  init_tws(twr,twi);
  int bi = blockIdx.x;
  float2* base; int ri;
  if (bi < 4608){ base = V; ri = bi; } else { base = L; ri = bi - 4608; }
  int rl=(int)threadIdx.x>>6, u=(int)threadIdx.x&63;
  float *xr=br+rl,*xi=bis+rl;
  float2* row = base + ((size_t)ri*4 + rl)*NSZ;
  #pragma unroll
  for (int k=0;k<6;k++){ int x=u+64*k; float2 v=row[x]; xr[x*5]=v.x; xi[x*5]=v.y; }
  __syncthreads();
  fftsb<5,-1>(xr,xi,u,twr,twi);
  #pragma unroll
  for (int k=0;k<6;k++){ int x=u+64*k; row[x]=make_float2(xr[x*5],xi[x*5]); }
}

// ---------------- streaming occlusion compositing (no FFT) ------------------
__global__ __launch_bounds__(256) void k_combine(const float2* __restrict__ L,
    const float2* __restrict__ V, float* __restrict__ out){
  int t = blockIdx.x*256 + (int)threadIdx.x;   // < 3*NPIX/2
  int c = t / (NPIX/2);
  int pp = t - c*(NPIX/2);                     // pixel-pair index
  size_t base = (size_t)(c*ND)*NPIX + (size_t)pp*2;
  float A0a=0.f,C0a=0.f,A1a=0.f,C1a=0.f;
  float A0b=0.f,C0b=0.f,A1b=0.f,C1b=0.f;
  for (int d=ND-1; d>=0; --d){
    float4 l = *(const float4*)(L + base + (size_t)d*NPIX);
    float4 v = *(const float4*)(V + base + (size_t)d*NPIX);
    A0a += l.x; A1a += l.y; A0b += l.z; A1b += l.w;
    float ic0a=1.f/(A0a+EPSV), ic1a=1.f/(A1a+EPSV);
    float ic0b=1.f/(A0b+EPSV), ic1b=1.f/(A1b+EPSV);
    C0a = v.x*ic0a + (1.f - l.x*ic0a)*C0a;
    C1a = v.y*ic1a + (1.f - l.y*ic1a)*C1a;
    C0b = v.z*ic0b + (1.f - l.z*ic0b)*C0b;
    C1b = v.w*ic1b + (1.f - l.w*ic1b)*C1b;
  }
  size_t o0 = (size_t)(0*3 + c)*NPIX + (size_t)pp*2;
  size_t o1 = (size_t)(1*3 + c)*NPIX + (size_t)pp*2;
  out[o0]   = C0a; out[o0+1] = C0b;
  out[o1]   = C1a; out[o1+1] = C1b;
}

extern "C" void kernel_launch(void* const* d_in, const int* in_sizes, int n_in,
                              void* d_out, int out_size, void* d_ws, size_t ws_size,
                              hipStream_t stream){
  const float* img   = (const float*)d_in[0];   // (2,3,384,384) f32
  const float* depth = (const float*)d_in[1];   // (2,1,384,384) f32
  const void*  h1d   = d_in[2];                 // (1024,)
  const void*  amp   = d_in[3];                 // (3,16,1024)
  const void*  pph   = d_in[4];                 // (3,16,1024)
  const void*  Hm    = d_in[5];                 // (3,1024,194)
  const void*  rg    = d_in[6];                 // (3,194)
  const void*  rs    = d_in[7];                 // (3,192,192)
  float* out = (float*)d_out;
  (void)in_sizes; (void)n_in; (void)out_size;

  char* ws = (char*)d_ws;
  size_t off = 0;
  auto take = [&](size_t b)->char*{ char* p = ws + off; off += (b + 255) & ~(size_t)255; return p; };
  double*  sums = (double*) take((size_t)48*8);
  double2* part = (double2*)take((size_t)48*8*NG*16);     //  1.19 MB
  float*   q    = (float*)  take((size_t)48*QPIX*4);      //  7.08 MB
  float*   Rr   = (float*)  take((size_t)48*192*NSZ*4);   // 14.16 MB
  float*   Rc   = (float*)  take((size_t)48*NPIX*4);      // 28.31 MB
  float2*  V    = (float2*) take((size_t)48*NPIX*8);      // 56.62 MB
  float2*  S    = (float2*) take((size_t)16*NPIX*8);      // 18.87 MB
  float2*  L    = (float2*) take((size_t)48*NPIX*8);      // 56.62 MB
  if (ws_size < off) return;   // ~183 MB; clean absmax failure, not a fault

  hipMemsetAsync(sums, 0, 48*8, stream);
  k_dotA<<<48*8, 256, 0, stream>>>(h1d, amp, pph, Hm, rg, part);
  k_interp2<<<48*144, 256, 0, stream>>>(part, rg, rs, q, sums);
  k_rows_fwd<<<48*24 + 48*96 + 16*96, 256, 0, stream>>>(q, sums, Rr, img, depth, V, S);
  k_colsFS<<<1152 + 16*48, 512, 0, stream>>>(Rr, Rc, S);
  k_FM<<<48*48 + 3*16*48, 512, 0, stream>>>(V, Rc, S, L, 48*48);
  k_rowsinv<<<9216, 256, 0, stream>>>(V, L);
  k_combine<<<864, 256, 0, stream>>>(L, V, out);
}